// Round 1
// baseline (34.817 us; speedup 1.0000x reference)
//
#include <hip/hip_runtime.h>
#include <math.h>

// Bundle-adjustment edge reprojection:
// per edge e: gather pose (7f) and patch (r,theta)+phi, spherical->cart,
// quaternion-rotate + translate, cart->polar(r, atan2), subtract target.

#define EDGE_COUNT 1048576

__global__ __launch_bounds__(256) void ba_edge_kernel(
    const float*  __restrict__ poses,         // [8192*7]
    const float2* __restrict__ patch_coords,  // [E] (r, theta)
    const float*  __restrict__ elev,          // [E] phi
    const float2* __restrict__ target,        // [E]
    const int*    __restrict__ poses_idx,     // [E]
    const int*    __restrict__ patch_idx,     // [E]
    float2*       __restrict__ out,           // [E]
    int n)
{
    int e = blockIdx.x * blockDim.x + threadIdx.x;
    if (e >= n) return;

    const int pi = poses_idx[e];
    const int ki = patch_idx[e];

    const float2 rt  = patch_coords[ki];
    const float  phi = elev[ki];
    const float  r = rt.x, theta = rt.y;

    float sphi, cphi, st, ct;
    __sincosf(phi,   &sphi, &cphi);
    __sincosf(theta, &st,   &ct);

    const float rc = r * cphi;
    const float px = rc * ct;
    const float py = rc * st;
    const float pz = r * sphi;

    const float* p = poses + pi * 7;
    const float tx = p[0], ty = p[1], tz = p[2];
    const float qx = p[3], qy = p[4], qz = p[5], qw = p[6];

    // uv = cross(qv, pts)
    const float ux = qy * pz - qz * py;
    const float uy = qz * px - qx * pz;
    const float uz = qx * py - qy * px;
    // cc = cross(qv, uv)
    const float cx = qy * uz - qz * uy;
    const float cy = qz * ux - qx * uz;
    const float cz = qx * uy - qy * ux;

    const float x = px + 2.0f * (qw * ux + cx) + tx;
    const float y = py + 2.0f * (qw * uy + cy) + ty;
    const float z = pz + 2.0f * (qw * uz + cz) + tz;

    const float r_out     = sqrtf(x * x + y * y + z * z);
    const float theta_out = atan2f(y, x);

    const float2 tg = target[e];
    out[e] = make_float2(r_out - tg.x, theta_out - tg.y);
}

extern "C" void kernel_launch(void* const* d_in, const int* in_sizes, int n_in,
                              void* d_out, int out_size, void* d_ws, size_t ws_size,
                              hipStream_t stream) {
    const float*  poses        = (const float*)d_in[0];   // 8192*7
    const float2* patch_coords = (const float2*)d_in[1];  // E*2 floats
    const float*  elev         = (const float*)d_in[2];   // E
    const float2* target       = (const float2*)d_in[3];  // E*2 floats
    const int*    poses_idx    = (const int*)d_in[4];     // E
    const int*    patch_idx    = (const int*)d_in[5];     // E

    const int n = in_sizes[4];  // EDGE_NUM
    float2* out = (float2*)d_out;

    const int block = 256;
    const int grid  = (n + block - 1) / block;
    ba_edge_kernel<<<grid, block, 0, stream>>>(
        poses, patch_coords, elev, target, poses_idx, patch_idx, out, n);
}